// Round 3
// baseline (534.004 us; speedup 1.0000x reference)
//
#include <hip/hip_runtime.h>
#include <stdint.h>

#define N_PART   100000
#define N_FRAMES 500

__device__ __forceinline__ uint32_t rotl32(uint32_t v, int d) {
    return (v << d) | (v >> (32 - d));
}

// JAX threefry2x32, 20 rounds, exact port of jax/_src/prng.py
#define TF_ROUND(r) { x0 += x1; x1 = rotl32(x1, (r)); x1 ^= x0; }

__device__ __forceinline__ void tf2x32(uint32_t k0, uint32_t k1,
                                       uint32_t x0, uint32_t x1,
                                       uint32_t &o0, uint32_t &o1) {
    const uint32_t k2 = k0 ^ k1 ^ 0x1BD11BDAu;
    x0 += k0; x1 += k1;
    TF_ROUND(13) TF_ROUND(15) TF_ROUND(26) TF_ROUND(6)
    x0 += k1; x1 += k2 + 1u;
    TF_ROUND(17) TF_ROUND(29) TF_ROUND(16) TF_ROUND(24)
    x0 += k2; x1 += k0 + 2u;
    TF_ROUND(13) TF_ROUND(15) TF_ROUND(26) TF_ROUND(6)
    x0 += k0; x1 += k1 + 3u;
    TF_ROUND(17) TF_ROUND(29) TF_ROUND(16) TF_ROUND(24)
    x0 += k1; x1 += k2 + 4u;
    TF_ROUND(13) TF_ROUND(15) TF_ROUND(26) TF_ROUND(6)
    x0 += k2; x1 += k0 + 5u;
    o0 = x0; o1 = x1;
}

// partitionable random_bits(key, 32, shape): bits[idx] = o0^o1 of tf(key,(0,idx))
__device__ __forceinline__ float uniform_from_bits(uint32_t bits) {
    return __uint_as_float((bits >> 9) | 0x3f800000u) - 1.0f;
}

__global__ __launch_bounds__(256)
void hmm_kernel(const float* __restrict__ initial,
                const int* __restrict__ seed_ptr,
                float* __restrict__ out) {
    __shared__ uint32_t skey0[N_FRAMES];
    __shared__ uint32_t skey1[N_FRAMES];
    __shared__ float sp;

    const int tid = threadIdx.x;
    const uint32_t seed_lo = (uint32_t)seed_ptr[0];
    const uint32_t seed_hi = 0u;

    // split(key) foldlike: kp = tf(key,(0,0)), ks = tf(key,(0,1))
    uint32_t ks0, ks1;
    tf2x32(seed_hi, seed_lo, 0u, 1u, ks0, ks1);

    // keys[t] = tf(ks, (0, t))
    for (int t = tid; t < N_FRAMES; t += blockDim.x) {
        uint32_t a, b;
        tf2x32(ks0, ks1, 0u, (uint32_t)t, a, b);
        skey0[t] = a;
        skey1[t] = b;
    }
    if (tid == 0) {
        uint32_t kp0, kp1, b0, b1;
        tf2x32(seed_hi, seed_lo, 0u, 0u, kp0, kp1);
        tf2x32(kp0, kp1, 0u, 0u, b0, b1);
        sp = uniform_from_bits(b0 ^ b1) * 0.001f;
    }
    __syncthreads();

    const int n = blockIdx.x * blockDim.x + tid;
    if (n >= N_PART) return;

    const float p  = sp;    // P(flip | state==1)
    const float p0 = 0.2f;  // P(flip | state==0)

    int s = (initial[2 * n + 1] > 0.5f) ? 1 : 0;
    const uint32_t base = 2u * (uint32_t)n;

    float2* __restrict__ outv = (float2*)out;
    const float2 oh0 = make_float2(1.0f, 0.0f);
    const float2 oh1 = make_float2(0.0f, 1.0f);

    // K=2 speculative: per frame pair, 3 INDEPENDENT threefry chains
    // (frame t at known s; frame t+1 at both possible states) -> 3-way ILP,
    // 1.5x eval work, dependent-latency fully hidden.
    for (int t = 0; t < N_FRAMES; t += 2) {
        const uint32_t ka0 = skey0[t],     ka1 = skey1[t];
        const uint32_t kb0 = skey0[t + 1], kb1 = skey1[t + 1];

        uint32_t a0, a1, c00, c01, c10, c11;
        tf2x32(ka0, ka1, 0u, base + (uint32_t)s, a0, a1);  // frame t, known s
        tf2x32(kb0, kb1, 0u, base,               c00, c01); // frame t+1, s=0
        tf2x32(kb0, kb1, 0u, base + 1u,          c10, c11); // frame t+1, s=1

        const float uA = uniform_from_bits(a0 ^ a1);
        s ^= (uA < (s ? p : p0)) ? 1 : 0;
        outv[(size_t)t * N_PART + n] = s ? oh1 : oh0;

        const float uB = uniform_from_bits(s ? (c10 ^ c11) : (c00 ^ c01));
        s ^= (uB < (s ? p : p0)) ? 1 : 0;
        outv[(size_t)(t + 1) * N_PART + n] = s ? oh1 : oh0;
    }
}

extern "C" void kernel_launch(void* const* d_in, const int* in_sizes, int n_in,
                              void* d_out, int out_size, void* d_ws, size_t ws_size,
                              hipStream_t stream) {
    const float* initial = (const float*)d_in[0];
    const int*   seed    = (const int*)d_in[1];
    float*       out     = (float*)d_out;

    const int block = 256;
    const int grid = (N_PART + block - 1) / block;
    hmm_kernel<<<grid, block, 0, stream>>>(initial, seed, out);
}